// Round 1
// baseline (921.791 us; speedup 1.0000x reference)
//
#include <hip/hip_runtime.h>
#include <stdint.h>

// DSMIL forward on MI355X.
// Pipeline: cast(x,w1,w2,wv->bf16) -> GEMM1(relu) -> GEMM2(relu) ->
//   instance_pred -> argmax -> q_max -> t=q_max@w_q -> GEMM3(V + 2 logit cols)
//   -> softmax reduce -> A + B=A^T V -> C (conv1d k=1024).
// Q-GEMM eliminated: logits = feat @ (w_q^T q_max_c) + const_c, const cancels
// in softmax over axis 0.

typedef unsigned short u16;
typedef __attribute__((ext_vector_type(8))) short short8;
typedef __attribute__((ext_vector_type(4))) float floatx4;

#define TILE 128
#define BK 32

__device__ __forceinline__ float bf2f(u16 u) {
  union { unsigned u; float f; } x; x.u = ((unsigned)u) << 16; return x.f;
}
__device__ __forceinline__ u16 f2bf(float f) {
  union { float f; unsigned u; } x; x.f = f;
  return (u16)((x.u + 0x7fffu + ((x.u >> 16) & 1u)) >> 16);  // RNE
}
__device__ __forceinline__ unsigned ordf(float f) {
  union { float f; unsigned u; } x; x.f = f;
  return (x.u & 0x80000000u) ? ~x.u : (x.u | 0x80000000u);
}
__device__ __forceinline__ void gload16(const void* g, void* l) {
  __builtin_amdgcn_global_load_lds(
      (const __attribute__((address_space(1))) void*)g,
      (__attribute__((address_space(3))) void*)l, 16, 0, 0);
}

// ---------------- bf16 MFMA GEMM, C = A[M,K] * B[N,K]^T -------------------
// MODE 0: out = bf16(relu(acc + bias[col])), ld=ldo
// MODE 1: cols <1024: out = bf16(acc + bias[col]) (V); col tile 8 (1024..1151):
//         cols 1024/1025 -> fp32 logits [M,2], no bias.
template <int MODE>
__global__ __launch_bounds__(256) void gemm_bt(
    const u16* __restrict__ A, const u16* __restrict__ B,
    const float* __restrict__ bias, u16* __restrict__ O,
    float* __restrict__ OL, int K, int ntiles, int ldo) {
  __shared__ __align__(16) u16 As[TILE * BK];
  __shared__ __align__(16) u16 Bs[TILE * BK];

  const int nt = blockIdx.x % ntiles;
  const int mt = blockIdx.x / ntiles;
  const int m0 = mt * TILE, n0 = nt * TILE;
  const int tid = threadIdx.x;
  const int lane = tid & 63;
  const int wm = (tid >> 7) * 64;        // wave row quadrant
  const int wn = ((tid >> 6) & 1) * 64;  // wave col quadrant

  floatx4 acc[4][4];
#pragma unroll
  for (int i = 0; i < 4; ++i)
#pragma unroll
    for (int j = 0; j < 4; ++j) acc[i][j] = (floatx4){0.f, 0.f, 0.f, 0.f};

  // staging: 256 thr x 16B x 2 rounds per tile (8KB). LDS dest is
  // wave-uniform base + lane*16 -- layout matches row-major [128][32].
  const int srow = tid >> 2;
  const int scol = (tid & 3) * 8;
  const u16* Ag0 = A + (size_t)(m0 + srow) * K + scol;
  const u16* Ag1 = Ag0 + (size_t)64 * K;
  const u16* Bg0 = B + (size_t)(n0 + srow) * K + scol;
  const u16* Bg1 = Bg0 + (size_t)64 * K;
  u16* Al0 = As + tid * 8;
  u16* Al1 = Al0 + 256 * 8;
  u16* Bl0 = Bs + tid * 8;
  u16* Bl1 = Bl0 + 256 * 8;

  // fragment base: A[m=lane&15][k=quad*8+j]
  const u16* Af = As + (size_t)(wm + (lane & 15)) * BK + ((lane >> 4) * 8);
  const u16* Bf = Bs + (size_t)(wn + (lane & 15)) * BK + ((lane >> 4) * 8);

  const int kiters = K / BK;
  for (int kt = 0; kt < kiters; ++kt) {
    gload16(Ag0, Al0); gload16(Ag1, Al1);
    gload16(Bg0, Bl0); gload16(Bg1, Bl1);
    Ag0 += BK; Ag1 += BK; Bg0 += BK; Bg1 += BK;
    __syncthreads();  // compiler emits vmcnt(0) drain before barrier
    short8 a[4], b[4];
#pragma unroll
    for (int f = 0; f < 4; ++f) {
      a[f] = *(const short8*)(Af + f * 16 * BK);
      b[f] = *(const short8*)(Bf + f * 16 * BK);
    }
#pragma unroll
    for (int i = 0; i < 4; ++i)
#pragma unroll
      for (int j = 0; j < 4; ++j)
        acc[i][j] = __builtin_amdgcn_mfma_f32_16x16x32_bf16(a[i], b[j],
                                                            acc[i][j], 0, 0, 0);
    __syncthreads();
  }

  // C layout: col = lane&15, row = (lane>>4)*4 + reg  (m89/m91 verified)
  const int er = (lane >> 4) * 4;
  const int ec = lane & 15;
  if (MODE == 0 || n0 < 1024) {
#pragma unroll
    for (int j = 0; j < 4; ++j) {
      const int col = n0 + wn + j * 16 + ec;
      const float bv = bias[col];
#pragma unroll
      for (int i = 0; i < 4; ++i) {
        const int row = m0 + wm + i * 16 + er;
#pragma unroll
        for (int r = 0; r < 4; ++r) {
          float v = acc[i][j][r] + bv;
          if (MODE == 0) v = fmaxf(v, 0.f);
          O[(size_t)(row + r) * ldo + col] = f2bf(v);
        }
      }
    }
  } else {  // logits tile: only cols 1024,1025 live (wn==0, frag j==0, ec<2)
    if (wn == 0 && ec < 2) {
#pragma unroll
      for (int i = 0; i < 4; ++i) {
        const int row = m0 + wm + i * 16 + er;
#pragma unroll
        for (int r = 0; r < 4; ++r)
          OL[(size_t)(row + r) * 2 + ec] = acc[i][0][r];
      }
    }
  }
}

// ---------------- glue kernels ---------------------------------------------
__global__ void k_init(u16* b3pad, float* Bbuf, unsigned long long* keys) {
  int i = blockIdx.x * 256 + threadIdx.x;
  if (i < 129024) b3pad[i] = 0;   // B3 rows 1026..1151 zero
  if (i < 2048) Bbuf[i] = 0.f;
  if (i < 2) keys[i] = 0ull;
}

__global__ void k_cast(const float* __restrict__ s, u16* __restrict__ d, int n4) {
  int i = blockIdx.x * 256 + threadIdx.x;
  if (i >= n4) return;
  float4 v = ((const float4*)s)[i];
  unsigned long long o = (unsigned long long)f2bf(v.x) |
                         ((unsigned long long)f2bf(v.y) << 16) |
                         ((unsigned long long)f2bf(v.z) << 32) |
                         ((unsigned long long)f2bf(v.w) << 48);
  ((unsigned long long*)d)[i] = o;
}

// instance_pred[row,c] = feat[row,:] . wfc[c,:] + bfc[c]; one wave per row
__global__ __launch_bounds__(256) void k_ip(const u16* __restrict__ feat,
                                            const float* __restrict__ wfc,
                                            const float* __restrict__ bfc,
                                            float* __restrict__ out_ip) {
  const int row = blockIdx.x * 4 + (threadIdx.x >> 6);
  const int lane = threadIdx.x & 63;
  const u16* fr = feat + (size_t)row * 1024 + lane * 16;
  const float* w0 = wfc + lane * 16;
  const float* w1 = wfc + 1024 + lane * 16;
  float s0 = 0.f, s1 = 0.f;
#pragma unroll
  for (int t = 0; t < 16; ++t) {
    float f = bf2f(fr[t]);
    s0 += f * w0[t];
    s1 += f * w1[t];
  }
#pragma unroll
  for (int off = 32; off > 0; off >>= 1) {
    s0 += __shfl_down(s0, off, 64);
    s1 += __shfl_down(s1, off, 64);
  }
  if (lane == 0) {
    out_ip[(size_t)row * 2 + 0] = s0 + bfc[0];
    out_ip[(size_t)row * 2 + 1] = s1 + bfc[1];
  }
}

// per-class argmax via encoded (ordered_val<<32)|(~idx) atomicMax
__global__ __launch_bounds__(256) void k_argmax(const float* __restrict__ ip,
                                                unsigned long long* __restrict__ keys) {
  float m0 = -1e30f, m1 = -1e30f;
  int i0 = 0, i1 = 0;
  for (int i = blockIdx.x * 256 + threadIdx.x; i < 32768; i += 256 * 64) {
    float v0 = ip[2 * i], v1 = ip[2 * i + 1];
    if (v0 > m0) { m0 = v0; i0 = i; }
    if (v1 > m1) { m1 = v1; i1 = i; }
  }
  unsigned long long k0 =
      ((unsigned long long)ordf(m0) << 32) | (0xFFFFFFFFu - (unsigned)i0);
  unsigned long long k1 =
      ((unsigned long long)ordf(m1) << 32) | (0xFFFFFFFFu - (unsigned)i1);
#pragma unroll
  for (int off = 32; off > 0; off >>= 1) {
    unsigned long long t0 = __shfl_down(k0, off, 64);
    unsigned long long t1 = __shfl_down(k1, off, 64);
    if (t0 > k0) k0 = t0;
    if (t1 > k1) k1 = t1;
  }
  __shared__ unsigned long long s0[4], s1[4];
  const int lane = threadIdx.x & 63, wv = threadIdx.x >> 6;
  if (lane == 0) { s0[wv] = k0; s1[wv] = k1; }
  __syncthreads();
  if (threadIdx.x == 0) {
    for (int w = 1; w < 4; ++w) {
      if (s0[w] > k0) k0 = s0[w];
      if (s1[w] > k1) k1 = s1[w];
    }
    atomicMax(keys + 0, k0);
    atomicMax(keys + 1, k1);
  }
}

// q_max[c,k] = feat[idx_c,:] . wq[k,:] + bq[k]; one wave per (c,k)
__global__ __launch_bounds__(256) void k_qmax(const u16* __restrict__ feat,
                                              const float* __restrict__ wq,
                                              const float* __restrict__ bq,
                                              const unsigned long long* __restrict__ keys,
                                              float* __restrict__ qmax) {
  const int gw = blockIdx.x * 4 + (threadIdx.x >> 6);  // 0..2047
  const int c = gw >> 10, k = gw & 1023;
  const int lane = threadIdx.x & 63;
  const int idx = (int)(0xFFFFFFFFu - (unsigned)(keys[c] & 0xFFFFFFFFull));
  const u16* fr = feat + (size_t)idx * 1024 + lane * 16;
  const float* wr = wq + (size_t)k * 1024 + lane * 16;
  float s = 0.f;
#pragma unroll
  for (int t = 0; t < 16; ++t) s += bf2f(fr[t]) * wr[t];
#pragma unroll
  for (int off = 32; off > 0; off >>= 1) s += __shfl_down(s, off, 64);
  if (lane == 0) qmax[c * 1024 + k] = s + bq[k];
}

// t[c,j] = sum_k qmax[c,k] * wq[k,j]  -> bf16 into B3 rows 1024+c
__global__ __launch_bounds__(256) void k_t(const float* __restrict__ wq,
                                           const float* __restrict__ qmax,
                                           u16* __restrict__ b3) {
  const int c = blockIdx.x >> 2;
  const int j = (blockIdx.x & 3) * 256 + threadIdx.x;
  float s = 0.f;
  for (int k = 0; k < 1024; ++k) s += qmax[c * 1024 + k] * wq[(size_t)k * 1024 + j];
  b3[(size_t)(1024 + c) * 1024 + j] = f2bf(s);
}

// per-class max + sum(exp((l-max)/32)) over 32768 rows; one block
__global__ __launch_bounds__(256) void k_reduce(const float* __restrict__ lg,
                                                float* __restrict__ ms) {
  __shared__ float r0[256], r1[256];
  const int tid = threadIdx.x;
  float m0 = -1e30f, m1 = -1e30f;
  for (int i = tid; i < 32768; i += 256) {
    m0 = fmaxf(m0, lg[2 * i]);
    m1 = fmaxf(m1, lg[2 * i + 1]);
  }
  r0[tid] = m0; r1[tid] = m1;
  __syncthreads();
  for (int s = 128; s > 0; s >>= 1) {
    if (tid < s) {
      r0[tid] = fmaxf(r0[tid], r0[tid + s]);
      r1[tid] = fmaxf(r1[tid], r1[tid + s]);
    }
    __syncthreads();
  }
  m0 = r0[0]; m1 = r1[0];
  __syncthreads();
  float s0 = 0.f, s1 = 0.f;
  for (int i = tid; i < 32768; i += 256) {
    s0 += __expf((lg[2 * i] - m0) * 0.03125f);
    s1 += __expf((lg[2 * i + 1] - m1) * 0.03125f);
  }
  r0[tid] = s0; r1[tid] = s1;
  __syncthreads();
  for (int s = 128; s > 0; s >>= 1) {
    if (tid < s) { r0[tid] += r0[tid + s]; r1[tid] += r1[tid + s]; }
    __syncthreads();
  }
  if (tid == 0) { ms[0] = m0; ms[1] = m1; ms[2] = r0[0]; ms[3] = r1[0]; }
}

// A[i,c] = exp((l-max)/32)/sum -> out; B[c,:] += sum_i A[i,c] V[i,:] (atomics)
__global__ __launch_bounds__(256) void k_ab(const float* __restrict__ lg,
                                            const float* __restrict__ ms,
                                            const u16* __restrict__ V,
                                            float* __restrict__ outA,
                                            float* __restrict__ Bbuf) {
  const int tid = threadIdx.x;
  const int row0 = blockIdx.x * 256;
  const float m0 = ms[0], m1 = ms[1];
  const float inv0 = 1.f / ms[2], inv1 = 1.f / ms[3];
  {
    const int r = row0 + tid;
    outA[2 * r] = __expf((lg[2 * r] - m0) * 0.03125f) * inv0;
    outA[2 * r + 1] = __expf((lg[2 * r + 1] - m1) * 0.03125f) * inv1;
  }
  float p0[4] = {0, 0, 0, 0}, p1[4] = {0, 0, 0, 0};
  const int kb = tid * 4;
  for (int r = row0; r < row0 + 256; ++r) {
    const float a0 = __expf((lg[2 * r] - m0) * 0.03125f) * inv0;
    const float a1 = __expf((lg[2 * r + 1] - m1) * 0.03125f) * inv1;
    unsigned long long vv = *(const unsigned long long*)(V + (size_t)r * 1024 + kb);
    float f0 = bf2f((u16)vv), f1 = bf2f((u16)(vv >> 16));
    float f2 = bf2f((u16)(vv >> 32)), f3 = bf2f((u16)(vv >> 48));
    p0[0] += a0 * f0; p0[1] += a0 * f1; p0[2] += a0 * f2; p0[3] += a0 * f3;
    p1[0] += a1 * f0; p1[1] += a1 * f1; p1[2] += a1 * f2; p1[3] += a1 * f3;
  }
#pragma unroll
  for (int t = 0; t < 4; ++t) {
    atomicAdd(&Bbuf[kb + t], p0[t]);
    atomicAdd(&Bbuf[1024 + kb + t], p1[t]);
  }
}

// C[o] = sum_{i,k} wfcc[o,i,k]*B[i,k] + bfcc[o]; also copy B to out
__global__ __launch_bounds__(256) void k_c(const float* __restrict__ Bbuf,
                                           const float* __restrict__ wfcc,
                                           const float* __restrict__ bfcc,
                                           float* __restrict__ outC,
                                           float* __restrict__ outB) {
  __shared__ float r0[256], r1[256];
  const int tid = threadIdx.x;
  float s0 = 0.f, s1 = 0.f;
  for (int i = tid; i < 2048; i += 256) {
    float b = Bbuf[i];
    outB[i] = b;
    s0 += wfcc[i] * b;
    s1 += wfcc[2048 + i] * b;
  }
  r0[tid] = s0; r1[tid] = s1;
  __syncthreads();
  for (int s = 128; s > 0; s >>= 1) {
    if (tid < s) { r0[tid] += r0[tid + s]; r1[tid] += r1[tid + s]; }
    __syncthreads();
  }
  if (tid == 0) {
    outC[0] = r0[0] + bfcc[0];
    outC[1] = r1[0] + bfcc[1];
  }
}

extern "C" void kernel_launch(void* const* d_in, const int* in_sizes, int n_in,
                              void* d_out, int out_size, void* d_ws, size_t ws_size,
                              hipStream_t stream) {
  const float* x    = (const float*)d_in[0];
  const float* w1   = (const float*)d_in[1];
  const float* b1   = (const float*)d_in[2];
  const float* w2   = (const float*)d_in[3];
  const float* b2   = (const float*)d_in[4];
  const float* wfc  = (const float*)d_in[5];
  const float* bfc  = (const float*)d_in[6];
  const float* wq   = (const float*)d_in[7];
  const float* bq   = (const float*)d_in[8];
  const float* wv   = (const float*)d_in[9];
  const float* bv   = (const float*)d_in[10];
  const float* wfcc = (const float*)d_in[11];
  const float* bfcc = (const float*)d_in[12];

  float* out   = (float*)d_out;
  float* outIP = out;            // 65536
  float* outC  = out + 65536;    // 2
  float* outA  = out + 65538;    // 65536
  float* outB  = out + 131074;   // 2048

  char* ws = (char*)d_ws;
  u16* XB  = (u16*)(ws);                       // x bf16           113,246,208 B
  u16* HB  = (u16*)(ws + 113246208);           // h bf16, reused as V  67,108,864
  u16* FB  = (u16*)(ws + 180355072);           // feat bf16            67,108,864
  u16* W1B = (u16*)(ws + 247463936);           // w1 bf16               3,538,944
  u16* W2B = (u16*)(ws + 251002880);           // w2 bf16               2,097,152
  u16* B3  = (u16*)(ws + 253100032);           // [wv;t;pad] 1152x1024  2,359,296
  float* LG = (float*)(ws + 255459328);        // logits [32768,2]        262,144
  float* QM = (float*)(ws + 255721472);        // q_max [2,1024]            8,192
  unsigned long long* KEYS = (unsigned long long*)(ws + 255729664);  // 16
  float* MS   = (float*)(ws + 255729680);      // max0,max1,sum0,sum1       16
  float* BBUF = (float*)(ws + 255729696);      // B accum [2,1024]        8,192

  k_init<<<504, 256, 0, stream>>>(B3 + 1026 * 1024, BBUF, KEYS);
  k_cast<<<55296, 256, 0, stream>>>(x, XB, 56623104 / 4);
  k_cast<<<1728, 256, 0, stream>>>(w1, W1B, 1769472 / 4);
  k_cast<<<1024, 256, 0, stream>>>(w2, W2B, 1048576 / 4);
  k_cast<<<1024, 256, 0, stream>>>(wv, B3, 1048576 / 4);

  gemm_bt<0><<<256 * 8, 256, 0, stream>>>(XB, W1B, b1, HB, nullptr, 1728, 8, 1024);
  gemm_bt<0><<<256 * 8, 256, 0, stream>>>(HB, W2B, b2, FB, nullptr, 1024, 8, 1024);

  k_ip<<<8192, 256, 0, stream>>>(FB, wfc, bfc, outIP);
  k_argmax<<<64, 256, 0, stream>>>(outIP, KEYS);
  k_qmax<<<512, 256, 0, stream>>>(FB, wq, bq, KEYS, QM);
  k_t<<<8, 256, 0, stream>>>(wq, QM, B3);

  gemm_bt<1><<<256 * 9, 256, 0, stream>>>(FB, B3, bv, HB, LG, 1024, 9, 1024);

  k_reduce<<<1, 256, 0, stream>>>(LG, MS);
  k_ab<<<128, 256, 0, stream>>>(LG, MS, HB, outA, BBUF);
  k_c<<<1, 256, 0, stream>>>(BBUF, wfcc, bfcc, outC, outB);
}

// Round 2
// 854.338 us; speedup vs baseline: 1.0790x; 1.0790x over previous
//
#include <hip/hip_runtime.h>
#include <stdint.h>

// DSMIL forward on MI355X.
// Pipeline: cast(x,w1,w2,wv->bf16) -> GEMM1(relu) -> GEMM2(relu) ->
//   instance_pred -> argmax -> q_max -> t=q_max@w_q -> GEMM3(V + 2 logit cols)
//   -> softmax reduce -> A + B=A^T V -> C (conv1d k=1024).
// Q-GEMM eliminated: logits = feat @ (w_q^T q_max_c) + const_c, const cancels
// in softmax over axis 0.
// R2: XCD-aware block swizzle (blocks sharing an A tile land on one XCD's L2),
//     LDS +row chunk swizzle (breaks 4-8 way fragment-read bank conflicts),
//     k_t parallelized (32-block k-split), k_ab widened to 256 blocks.

typedef unsigned short u16;
typedef __attribute__((ext_vector_type(8))) short short8;
typedef __attribute__((ext_vector_type(4))) float floatx4;

#define TILE 128
#define BK 32

__device__ __forceinline__ float bf2f(u16 u) {
  union { unsigned u; float f; } x; x.u = ((unsigned)u) << 16; return x.f;
}
__device__ __forceinline__ u16 f2bf(float f) {
  union { float f; unsigned u; } x; x.f = f;
  return (u16)((x.u + 0x7fffu + ((x.u >> 16) & 1u)) >> 16);  // RNE
}
__device__ __forceinline__ unsigned ordf(float f) {
  union { float f; unsigned u; } x; x.f = f;
  return (x.u & 0x80000000u) ? ~x.u : (x.u | 0x80000000u);
}
__device__ __forceinline__ void gload16(const void* g, void* l) {
  __builtin_amdgcn_global_load_lds(
      (const __attribute__((address_space(1))) void*)g,
      (__attribute__((address_space(3))) void*)l, 16, 0, 0);
}

// ---------------- bf16 MFMA GEMM, C = A[M,K] * B[N,K]^T -------------------
// Grid MUST be divisible by 8*ntiles.
// MODE 0: out = bf16(relu(acc + bias[col])), ld=ldo
// MODE 1: cols <1024: out = bf16(acc + bias[col]) (V); col tile 8 (1024..1151):
//         cols 1024/1025 -> fp32 logits [M,2], no bias.
template <int MODE>
__global__ __launch_bounds__(256) void gemm_bt(
    const u16* __restrict__ A, const u16* __restrict__ B,
    const float* __restrict__ bias, u16* __restrict__ O,
    float* __restrict__ OL, int K, int ntiles, int ldo) {
  __shared__ __align__(16) u16 As[TILE * BK];
  __shared__ __align__(16) u16 Bs[TILE * BK];

  // XCD swizzle: xcd = b&7 (round-robin dispatch). Within an XCD the
  // ntiles consecutive j's share one mt -> A tile cached in that XCD's L2.
  const int xcd = blockIdx.x & 7;
  const int j = blockIdx.x >> 3;
  const int mstride = gridDim.x / (ntiles << 3);
  const int mt = xcd * mstride + j / ntiles;
  const int nt = j % ntiles;
  const int m0 = mt * TILE, n0 = nt * TILE;
  const int tid = threadIdx.x;
  const int lane = tid & 63;
  const int wm = (tid >> 7) * 64;        // wave row quadrant
  const int wn = ((tid >> 6) & 1) * 64;  // wave col quadrant

  floatx4 acc[4][4];
#pragma unroll
  for (int i = 0; i < 4; ++i)
#pragma unroll
    for (int jf = 0; jf < 4; ++jf) acc[i][jf] = (floatx4){0.f, 0.f, 0.f, 0.f};

  // staging: 256 thr x 16B x 2 rounds per tile (8KB). LDS dest is
  // wave-uniform base + lane*16 (row-major [128][4 slots of 16B]).
  // Swizzle: LDS slot s of row r holds global chunk q = (s - r) & 3, so
  // fragment reads (rows 0..15 per phase) spread across 4 bank groups.
  // Source stays a permutation of 4 contiguous 16B chunks -> coalescing kept.
  const int srow = tid >> 2;
  const int sq = ((tid & 3) - srow) & 3;  // global k-chunk this thread fetches
  const u16* Ag0 = A + (size_t)(m0 + srow) * K + sq * 8;
  const u16* Ag1 = Ag0 + (size_t)64 * K;  // row+64 (64%4==0 -> same sq)
  const u16* Bg0 = B + (size_t)(n0 + srow) * K + sq * 8;
  const u16* Bg1 = Bg0 + (size_t)64 * K;
  u16* Al0 = As + tid * 8;
  u16* Al1 = Al0 + 256 * 8;
  u16* Bl0 = Bs + tid * 8;
  u16* Bl1 = Bl0 + 256 * 8;

  // fragment base: A[m=lane&15][k=quad*8+...], slot = (quad + row) & 3
  const int fr = lane & 15;
  const int fq = lane >> 4;
  const u16* Af = As + (size_t)(wm + fr) * BK + (((fq + fr) & 3) * 8);
  const u16* Bf = Bs + (size_t)(wn + fr) * BK + (((fq + fr) & 3) * 8);

  const int kiters = K / BK;
  for (int kt = 0; kt < kiters; ++kt) {
    gload16(Ag0, Al0); gload16(Ag1, Al1);
    gload16(Bg0, Bl0); gload16(Bg1, Bl1);
    Ag0 += BK; Ag1 += BK; Bg0 += BK; Bg1 += BK;
    __syncthreads();
    short8 a[4], b[4];
#pragma unroll
    for (int f = 0; f < 4; ++f) {  // row += 16 (0 mod 4) -> slot unchanged
      a[f] = *(const short8*)(Af + f * 16 * BK);
      b[f] = *(const short8*)(Bf + f * 16 * BK);
    }
#pragma unroll
    for (int i = 0; i < 4; ++i)
#pragma unroll
      for (int jf = 0; jf < 4; ++jf)
        acc[i][jf] = __builtin_amdgcn_mfma_f32_16x16x32_bf16(a[i], b[jf],
                                                             acc[i][jf], 0, 0, 0);
    __syncthreads();
  }

  // C layout: col = lane&15, row = (lane>>4)*4 + reg  (m89/m91 verified)
  const int er = (lane >> 4) * 4;
  const int ec = lane & 15;
  if (MODE == 0 || n0 < 1024) {
#pragma unroll
    for (int jf = 0; jf < 4; ++jf) {
      const int col = n0 + wn + jf * 16 + ec;
      const float bv = bias[col];
#pragma unroll
      for (int i = 0; i < 4; ++i) {
        const int row = m0 + wm + i * 16 + er;
#pragma unroll
        for (int r = 0; r < 4; ++r) {
          float v = acc[i][jf][r] + bv;
          if (MODE == 0) v = fmaxf(v, 0.f);
          O[(size_t)(row + r) * ldo + col] = f2bf(v);
        }
      }
    }
  } else {  // logits tile: only cols 1024,1025 live (wn==0, frag j==0, ec<2)
    if (wn == 0 && ec < 2) {
#pragma unroll
      for (int i = 0; i < 4; ++i) {
        const int row = m0 + wm + i * 16 + er;
#pragma unroll
        for (int r = 0; r < 4; ++r)
          OL[(size_t)(row + r) * 2 + ec] = acc[i][0][r];
      }
    }
  }
}

// ---------------- glue kernels ---------------------------------------------
__global__ void k_init(u16* b3pad, float* Bbuf, unsigned long long* keys) {
  int i = blockIdx.x * 256 + threadIdx.x;
  if (i < 129024) b3pad[i] = 0;   // B3 rows 1026..1151 zero
  if (i < 2048) Bbuf[i] = 0.f;
  if (i < 2) keys[i] = 0ull;
}

__global__ void k_cast(const float* __restrict__ s, u16* __restrict__ d, int n4) {
  int i = blockIdx.x * 256 + threadIdx.x;
  if (i >= n4) return;
  float4 v = ((const float4*)s)[i];
  unsigned long long o = (unsigned long long)f2bf(v.x) |
                         ((unsigned long long)f2bf(v.y) << 16) |
                         ((unsigned long long)f2bf(v.z) << 32) |
                         ((unsigned long long)f2bf(v.w) << 48);
  ((unsigned long long*)d)[i] = o;
}

// instance_pred[row,c] = feat[row,:] . wfc[c,:] + bfc[c]; one wave per row
__global__ __launch_bounds__(256) void k_ip(const u16* __restrict__ feat,
                                            const float* __restrict__ wfc,
                                            const float* __restrict__ bfc,
                                            float* __restrict__ out_ip) {
  const int row = blockIdx.x * 4 + (threadIdx.x >> 6);
  const int lane = threadIdx.x & 63;
  const u16* fr = feat + (size_t)row * 1024 + lane * 16;
  const float* w0 = wfc + lane * 16;
  const float* w1 = wfc + 1024 + lane * 16;
  float s0 = 0.f, s1 = 0.f;
#pragma unroll
  for (int t = 0; t < 16; ++t) {
    float f = bf2f(fr[t]);
    s0 += f * w0[t];
    s1 += f * w1[t];
  }
#pragma unroll
  for (int off = 32; off > 0; off >>= 1) {
    s0 += __shfl_down(s0, off, 64);
    s1 += __shfl_down(s1, off, 64);
  }
  if (lane == 0) {
    out_ip[(size_t)row * 2 + 0] = s0 + bfc[0];
    out_ip[(size_t)row * 2 + 1] = s1 + bfc[1];
  }
}

// per-class argmax via encoded (ordered_val<<32)|(~idx) atomicMax
__global__ __launch_bounds__(256) void k_argmax(const float* __restrict__ ip,
                                                unsigned long long* __restrict__ keys) {
  float m0 = -1e30f, m1 = -1e30f;
  int i0 = 0, i1 = 0;
  for (int i = blockIdx.x * 256 + threadIdx.x; i < 32768; i += 256 * 64) {
    float v0 = ip[2 * i], v1 = ip[2 * i + 1];
    if (v0 > m0) { m0 = v0; i0 = i; }
    if (v1 > m1) { m1 = v1; i1 = i; }
  }
  unsigned long long k0 =
      ((unsigned long long)ordf(m0) << 32) | (0xFFFFFFFFu - (unsigned)i0);
  unsigned long long k1 =
      ((unsigned long long)ordf(m1) << 32) | (0xFFFFFFFFu - (unsigned)i1);
#pragma unroll
  for (int off = 32; off > 0; off >>= 1) {
    unsigned long long t0 = __shfl_down(k0, off, 64);
    unsigned long long t1 = __shfl_down(k1, off, 64);
    if (t0 > k0) k0 = t0;
    if (t1 > k1) k1 = t1;
  }
  __shared__ unsigned long long s0[4], s1[4];
  const int lane = threadIdx.x & 63, wv = threadIdx.x >> 6;
  if (lane == 0) { s0[wv] = k0; s1[wv] = k1; }
  __syncthreads();
  if (threadIdx.x == 0) {
    for (int w = 1; w < 4; ++w) {
      if (s0[w] > k0) k0 = s0[w];
      if (s1[w] > k1) k1 = s1[w];
    }
    atomicMax(keys + 0, k0);
    atomicMax(keys + 1, k1);
  }
}

// q_max[c,k] = feat[idx_c,:] . wq[k,:] + bq[k]; one wave per (c,k)
__global__ __launch_bounds__(256) void k_qmax(const u16* __restrict__ feat,
                                              const float* __restrict__ wq,
                                              const float* __restrict__ bq,
                                              const unsigned long long* __restrict__ keys,
                                              float* __restrict__ qmax) {
  const int gw = blockIdx.x * 4 + (threadIdx.x >> 6);  // 0..2047
  const int c = gw >> 10, k = gw & 1023;
  const int lane = threadIdx.x & 63;
  const int idx = (int)(0xFFFFFFFFu - (unsigned)(keys[c] & 0xFFFFFFFFull));
  const u16* fr = feat + (size_t)idx * 1024 + lane * 16;
  const float* wr = wq + (size_t)k * 1024 + lane * 16;
  float s = 0.f;
#pragma unroll
  for (int t = 0; t < 16; ++t) s += bf2f(fr[t]) * wr[t];
#pragma unroll
  for (int off = 32; off > 0; off >>= 1) s += __shfl_down(s, off, 64);
  if (lane == 0) qmax[c * 1024 + k] = s + bq[k];
}

// t[c,j] = sum_k qmax[c,k]*wq[k,j]. 32 blocks: kp=b>>2 (8 k-parts of 128),
// jb=b&3 (4 j-bands of 256). Plain-store partials (no init needed).
__global__ __launch_bounds__(256) void k_t(const float* __restrict__ wq,
                                           const float* __restrict__ qmax,
                                           float* __restrict__ tpart) {
  const int jb = blockIdx.x & 3, kp = blockIdx.x >> 2;
  const int jcol = jb * 256 + threadIdx.x;
  float s0 = 0.f, s1 = 0.f;
  for (int k = kp * 128; k < kp * 128 + 128; ++k) {
    float w = wq[(size_t)k * 1024 + jcol];
    s0 += qmax[k] * w;
    s1 += qmax[1024 + k] * w;
  }
  tpart[kp * 2048 + jcol] = s0;
  tpart[kp * 2048 + 1024 + jcol] = s1;
}

// reduce 8 k-partials -> bf16 into B3 rows 1024+c
__global__ __launch_bounds__(256) void k_tcast(const float* __restrict__ tpart,
                                               u16* __restrict__ b3) {
  const int i = blockIdx.x * 256 + threadIdx.x;  // 0..2047: c=i>>10, j=i&1023
  float s = 0.f;
#pragma unroll
  for (int kp = 0; kp < 8; ++kp) s += tpart[kp * 2048 + i];
  b3[(size_t)(1024 + (i >> 10)) * 1024 + (i & 1023)] = f2bf(s);
}

// per-class max + sum(exp((l-max)/32)) over 32768 rows; one block
__global__ __launch_bounds__(256) void k_reduce(const float* __restrict__ lg,
                                                float* __restrict__ ms) {
  __shared__ float r0[256], r1[256];
  const int tid = threadIdx.x;
  float m0 = -1e30f, m1 = -1e30f;
  for (int i = tid; i < 32768; i += 256) {
    m0 = fmaxf(m0, lg[2 * i]);
    m1 = fmaxf(m1, lg[2 * i + 1]);
  }
  r0[tid] = m0; r1[tid] = m1;
  __syncthreads();
  for (int s = 128; s > 0; s >>= 1) {
    if (tid < s) {
      r0[tid] = fmaxf(r0[tid], r0[tid + s]);
      r1[tid] = fmaxf(r1[tid], r1[tid + s]);
    }
    __syncthreads();
  }
  m0 = r0[0]; m1 = r1[0];
  __syncthreads();
  float s0 = 0.f, s1 = 0.f;
  for (int i = tid; i < 32768; i += 256) {
    s0 += __expf((lg[2 * i] - m0) * 0.03125f);
    s1 += __expf((lg[2 * i + 1] - m1) * 0.03125f);
  }
  r0[tid] = s0; r1[tid] = s1;
  __syncthreads();
  for (int s = 128; s > 0; s >>= 1) {
    if (tid < s) { r0[tid] += r0[tid + s]; r1[tid] += r1[tid + s]; }
    __syncthreads();
  }
  if (tid == 0) { ms[0] = m0; ms[1] = m1; ms[2] = r0[0]; ms[3] = r1[0]; }
}

// A[i,c] = exp((l-max)/32)/sum -> out; B[c,:] += sum_i A[i,c] V[i,:] (atomics)
// 256 blocks x 128 rows.
__global__ __launch_bounds__(256) void k_ab(const float* __restrict__ lg,
                                            const float* __restrict__ ms,
                                            const u16* __restrict__ V,
                                            float* __restrict__ outA,
                                            float* __restrict__ Bbuf) {
  const int tid = threadIdx.x;
  const int row0 = blockIdx.x * 128;
  const float m0 = ms[0], m1 = ms[1];
  const float inv0 = 1.f / ms[2], inv1 = 1.f / ms[3];
  {
    const int r = row0 + (tid >> 1);
    const int c = tid & 1;
    outA[2 * r + c] =
        __expf((lg[2 * r + c] - (c ? m1 : m0)) * 0.03125f) * (c ? inv1 : inv0);
  }
  float p0[4] = {0, 0, 0, 0}, p1[4] = {0, 0, 0, 0};
  const int kb = tid * 4;
  for (int r = row0; r < row0 + 128; ++r) {
    const float a0 = __expf((lg[2 * r] - m0) * 0.03125f) * inv0;
    const float a1 = __expf((lg[2 * r + 1] - m1) * 0.03125f) * inv1;
    unsigned long long vv = *(const unsigned long long*)(V + (size_t)r * 1024 + kb);
    float f0 = bf2f((u16)vv), f1 = bf2f((u16)(vv >> 16));
    float f2 = bf2f((u16)(vv >> 32)), f3 = bf2f((u16)(vv >> 48));
    p0[0] += a0 * f0; p0[1] += a0 * f1; p0[2] += a0 * f2; p0[3] += a0 * f3;
    p1[0] += a1 * f0; p1[1] += a1 * f1; p1[2] += a1 * f2; p1[3] += a1 * f3;
  }
#pragma unroll
  for (int t = 0; t < 4; ++t) {
    atomicAdd(&Bbuf[kb + t], p0[t]);
    atomicAdd(&Bbuf[1024 + kb + t], p1[t]);
  }
}

// C[o] = sum_{i,k} wfcc[o,i,k]*B[i,k] + bfcc[o]; also copy B to out
__global__ __launch_bounds__(256) void k_c(const float* __restrict__ Bbuf,
                                           const float* __restrict__ wfcc,
                                           const float* __restrict__ bfcc,
                                           float* __restrict__ outC,
                                           float* __restrict__ outB) {
  __shared__ float r0[256], r1[256];
  const int tid = threadIdx.x;
  float s0 = 0.f, s1 = 0.f;
  for (int i = tid; i < 2048; i += 256) {
    float b = Bbuf[i];
    outB[i] = b;
    s0 += wfcc[i] * b;
    s1 += wfcc[2048 + i] * b;
  }
  r0[tid] = s0; r1[tid] = s1;
  __syncthreads();
  for (int s = 128; s > 0; s >>= 1) {
    if (tid < s) { r0[tid] += r0[tid + s]; r1[tid] += r1[tid + s]; }
    __syncthreads();
  }
  if (tid == 0) {
    outC[0] = r0[0] + bfcc[0];
    outC[1] = r1[0] + bfcc[1];
  }
}

extern "C" void kernel_launch(void* const* d_in, const int* in_sizes, int n_in,
                              void* d_out, int out_size, void* d_ws, size_t ws_size,
                              hipStream_t stream) {
  const float* x    = (const float*)d_in[0];
  const float* w1   = (const float*)d_in[1];
  const float* b1   = (const float*)d_in[2];
  const float* w2   = (const float*)d_in[3];
  const float* b2   = (const float*)d_in[4];
  const float* wfc  = (const float*)d_in[5];
  const float* bfc  = (const float*)d_in[6];
  const float* wq   = (const float*)d_in[7];
  const float* bq   = (const float*)d_in[8];
  const float* wv   = (const float*)d_in[9];
  const float* bv   = (const float*)d_in[10];
  const float* wfcc = (const float*)d_in[11];
  const float* bfcc = (const float*)d_in[12];

  float* out   = (float*)d_out;
  float* outIP = out;            // 65536
  float* outC  = out + 65536;    // 2
  float* outA  = out + 65538;    // 65536
  float* outB  = out + 131074;   // 2048

  char* ws = (char*)d_ws;
  u16* XB  = (u16*)(ws);                       // x bf16           113,246,208 B
  u16* HB  = (u16*)(ws + 113246208);           // h bf16, reused as V  67,108,864
  u16* FB  = (u16*)(ws + 180355072);           // feat bf16            67,108,864
  u16* W1B = (u16*)(ws + 247463936);           // w1 bf16 (dead after GEMM1)
  float* TPART = (float*)(ws + 247463936);     // k_t partials [8][2048] (reuses W1B)
  u16* W2B = (u16*)(ws + 251002880);           // w2 bf16               2,097,152
  u16* B3  = (u16*)(ws + 253100032);           // [wv;t;pad] 1152x1024  2,359,296
  float* LG = (float*)(ws + 255459328);        // logits [32768,2]        262,144
  float* QM = (float*)(ws + 255721472);        // q_max [2,1024]            8,192
  unsigned long long* KEYS = (unsigned long long*)(ws + 255729664);  // 16
  float* MS   = (float*)(ws + 255729680);      // max0,max1,sum0,sum1       16
  float* BBUF = (float*)(ws + 255729696);      // B accum [2,1024]        8,192

  k_init<<<504, 256, 0, stream>>>(B3 + 1026 * 1024, BBUF, KEYS);
  k_cast<<<55296, 256, 0, stream>>>(x, XB, 56623104 / 4);
  k_cast<<<1728, 256, 0, stream>>>(w1, W1B, 1769472 / 4);
  k_cast<<<1024, 256, 0, stream>>>(w2, W2B, 1048576 / 4);
  k_cast<<<1024, 256, 0, stream>>>(wv, B3, 1048576 / 4);

  gemm_bt<0><<<256 * 8, 256, 0, stream>>>(XB, W1B, b1, HB, nullptr, 1728, 8, 1024);
  gemm_bt<0><<<256 * 8, 256, 0, stream>>>(HB, W2B, b2, FB, nullptr, 1024, 8, 1024);

  k_ip<<<8192, 256, 0, stream>>>(FB, wfc, bfc, outIP);
  k_argmax<<<64, 256, 0, stream>>>(outIP, KEYS);
  k_qmax<<<512, 256, 0, stream>>>(FB, wq, bq, KEYS, QM);
  k_t<<<32, 256, 0, stream>>>(wq, QM, TPART);
  k_tcast<<<8, 256, 0, stream>>>(TPART, B3);

  gemm_bt<1><<<256 * 9, 256, 0, stream>>>(FB, B3, bv, HB, LG, 1024, 9, 1024);

  k_reduce<<<1, 256, 0, stream>>>(LG, MS);
  k_ab<<<256, 256, 0, stream>>>(LG, MS, HB, outA, BBUF);
  k_c<<<1, 256, 0, stream>>>(BBUF, wfcc, bfcc, outC, outB);
}